// Round 5
// baseline (287.070 us; speedup 1.0000x reference)
//
#include <hip/hip_runtime.h>
#include <stdint.h>

#define B_   4
#define N_   2048
#define M_   2048
#define DIN  512
#define DOUT 512
#define H_   8
#define HD_  64
#define ROWS (B_ * N_)   // 8192

typedef __attribute__((ext_vector_type(8))) short bf16x8;
typedef __attribute__((ext_vector_type(4))) float f32x4;
typedef __attribute__((ext_vector_type(2))) unsigned int u32x2;
typedef __attribute__((ext_vector_type(4))) unsigned short u16x4;
typedef unsigned short u16;
typedef unsigned int   u32;

#if __has_builtin(__builtin_amdgcn_exp2f)
#define EXP2(x) __builtin_amdgcn_exp2f(x)
#else
#define EXP2(x) exp2f(x)
#endif

__device__ __forceinline__ u16 f2bf(float x) {
  union { float f; u32 u; } v; v.f = x;
  u32 r = (v.u + 0x7FFFu + ((v.u >> 16) & 1u)) >> 16;
  return (u16)r;
}

__device__ __forceinline__ float bf2f(u16 x) {
  union { u32 u; float f; } v; v.u = ((u32)x) << 16;
  return v.f;
}

__device__ __forceinline__ u32 pkbf(float a, float b) {
  u32 r;
  asm("v_cvt_pk_bf16_f32 %0, %1, %2" : "=v"(r) : "v"(a), "v"(b));
  return r;
}

__device__ __forceinline__ void gld16(u16* lds, const u16* g) {
  __builtin_amdgcn_global_load_lds((const __attribute__((address_space(1))) u32*)g,
                                   (__attribute__((address_space(3))) u32*)lds, 16, 0, 0);
}

// ---------------- prep: f32 -> bf16 converts + balanced mask bit-pack ----------------
__global__ __launch_bounds__(256) void k_prep(
    const float* __restrict__ q, const float* __restrict__ k, const float* __restrict__ v,
    const float* __restrict__ wq_, const float* __restrict__ wk_,
    const float* __restrict__ wv_, const float* __restrict__ wo_,
    const int* __restrict__ mask,
    u16* __restrict__ qb, u16* __restrict__ kb, u16* __restrict__ vb,
    u16* __restrict__ wqb, u16* __restrict__ wkb, u16* __restrict__ wvb, u16* __restrict__ wob,
    u32* __restrict__ mbits)
{
  const int id = blockIdx.x;
  if (id >= 6656) {                      // mask pack: 16384 blocks x 4 waves x 4 iters x 64 ints
    const int id2 = id - 6656;
    const int lane = threadIdx.x & 63;
    const int gw = id2 * 4 + (threadIdx.x >> 6);      // 0..65535
    #pragma unroll
    for (int it2 = 0; it2 < 4; ++it2) {
      long pos = ((long)gw * 4 + it2) * 64 + lane;
      int mv = mask[pos];
      unsigned long long bal = __ballot(mv != 0);
      if ((lane & 31) == 0) mbits[pos >> 5] = (u32)(bal >> lane);
    }
    return;
  }
  const float* s; u16* d; size_t i;
  if (id < 6144) {                       // q/k/v: 3 x 4,194,304 elems
    const int seg = id >> 11;
    s = seg == 0 ? q : seg == 1 ? k : v;
    d = seg == 0 ? qb : seg == 1 ? kb : vb;
    i = (size_t)(id & 2047) * 2048 + threadIdx.x * 8;
  } else {                               // weights: 4 x 262,144 elems
    const int wid = id - 6144;
    const int seg = wid >> 7;
    s = seg == 0 ? wq_ : seg == 1 ? wk_ : seg == 2 ? wv_ : wo_;
    d = seg == 0 ? wqb : seg == 1 ? wkb : seg == 2 ? wvb : wob;
    i = (size_t)(wid & 127) * 2048 + threadIdx.x * 8;
  }
  f32x4 x = *(const f32x4*)(s + i);
  f32x4 y = *(const f32x4*)(s + i + 4);
  bf16x8 r;
  r[0] = (short)f2bf(x[0]); r[1] = (short)f2bf(x[1]);
  r[2] = (short)f2bf(x[2]); r[3] = (short)f2bf(x[3]);
  r[4] = (short)f2bf(y[0]); r[5] = (short)f2bf(y[1]);
  r[6] = (short)f2bf(y[2]); r[7] = (short)f2bf(y[3]);
  *(bf16x8*)(d + i) = r;
}

// ---------------- QKV projection GEMM (128x128 tile, BK=64), double-buffered ----------------
// z=0: Q [m][o] scaled by 0.125*log2(e); z=1: K [m][o]; z=2: V transposed [b*512+o][s].
__global__ __launch_bounds__(256) void k_gemm_qkv(
    const u16* __restrict__ Aq, const u16* __restrict__ Ak, const u16* __restrict__ Av,
    const u16* __restrict__ Wq, const u16* __restrict__ Wk, const u16* __restrict__ Wv,
    u16* __restrict__ Qo, u16* __restrict__ Ko, u16* __restrict__ Vt)
{
  __shared__ __align__(16) u16 At[2][128 * 64];
  __shared__ __align__(16) u16 Bt[2][128 * 64];
  const int z = blockIdx.z;
  const u16* A = z == 0 ? Aq : z == 1 ? Ak : Av;
  const u16* W = z == 0 ? Wq : z == 1 ? Wk : Wv;
  const int bm = blockIdx.y, bn = blockIdx.x;
  const int t = threadIdx.x, l = t & 63;
  const int w = t >> 6, wr = w >> 1, wc = w & 1;
  const int l15 = l & 15, lg = l >> 4;
  f32x4 acc[4][4] = {};
  const u16* ga = A + (size_t)(bm * 128 + (t >> 3)) * DIN + (t & 7) * 8;
  const u16* gb = W + (size_t)(bn * 128 + (t >> 3)) * DIN + (t & 7) * 8;

  #define STG(buf_, k0_) do {                                           \
    u16* la_ = &At[buf_][t * 8];                                        \
    u16* lb_ = &Bt[buf_][t * 8];                                        \
    _Pragma("unroll")                                                   \
    for (int s2 = 0; s2 < 4; ++s2) {                                    \
      gld16(la_ + s2 * 2048, ga + (size_t)s2 * 32 * DIN + (k0_));       \
      gld16(lb_ + s2 * 2048, gb + (size_t)s2 * 32 * DIN + (k0_));       \
    }                                                                   \
  } while (0)

  STG(0, 0);
  __syncthreads();
  for (int kt = 0; kt < 8; ++kt) {
    const int buf = kt & 1;
    if (kt + 1 < 8) STG(buf ^ 1, (kt + 1) * 64);
    const u16* rowT = (z < 2) ? &Bt[buf][wc * 64 * 64] : &At[buf][wr * 64 * 64];
    const u16* colT = (z < 2) ? &At[buf][wr * 64 * 64] : &Bt[buf][wc * 64 * 64];
    bf16x8 rf[4][2], cf[4][2];
    #pragma unroll
    for (int i = 0; i < 4; ++i)
      #pragma unroll
      for (int c = 0; c < 2; ++c)
        rf[i][c] = *(const bf16x8*)&rowT[(i * 16 + l15) * 64 + c * 32 + lg * 8];
    #pragma unroll
    for (int j = 0; j < 4; ++j)
      #pragma unroll
      for (int c = 0; c < 2; ++c)
        cf[j][c] = *(const bf16x8*)&colT[(j * 16 + l15) * 64 + c * 32 + lg * 8];
    #pragma unroll
    for (int i = 0; i < 4; ++i)
      #pragma unroll
      for (int j = 0; j < 4; ++j) {
        acc[i][j] = __builtin_amdgcn_mfma_f32_16x16x32_bf16(rf[i][0], cf[j][0], acc[i][j], 0, 0, 0);
        acc[i][j] = __builtin_amdgcn_mfma_f32_16x16x32_bf16(rf[i][1], cf[j][1], acc[i][j], 0, 0, 0);
      }
    __syncthreads();
  }
  #undef STG
  if (z < 2) {
    u16* C = z == 0 ? Qo : Ko;
    const float scl = z == 0 ? 0.18033688f : 1.0f;   // 1/sqrt(HD) * log2(e) folded into Q
    #pragma unroll
    for (int i = 0; i < 4; ++i) {
      const int o0 = bn * 128 + wc * 64 + i * 16 + lg * 4;
      #pragma unroll
      for (int j = 0; j < 4; ++j) {
        const int m = bm * 128 + wr * 64 + j * 16 + l15;
        u32x2 pr;
        pr[0] = pkbf(acc[i][j][0] * scl, acc[i][j][1] * scl);
        pr[1] = pkbf(acc[i][j][2] * scl, acc[i][j][3] * scl);
        *(u32x2*)&C[(size_t)m * DOUT + o0] = pr;
      }
    }
  } else {
    #pragma unroll
    for (int i = 0; i < 4; ++i) {
      const int mm = bm * 128 + wr * 64 + i * 16 + lg * 4;
      const int bb = mm >> 11, s = mm & 2047;
      #pragma unroll
      for (int j = 0; j < 4; ++j) {
        const int o = bn * 128 + wc * 64 + j * 16 + l15;
        u32x2 pr;
        pr[0] = pkbf(acc[i][j][0], acc[i][j][1]);
        pr[1] = pkbf(acc[i][j][2], acc[i][j][3]);
        *(u32x2*)&Vt[(size_t)(bb * 512 + o) * M_ + s] = pr;
      }
    }
  }
}

// ---------------- attention v5: 3-buffer counted-vmcnt pipeline ----------------
// Per iter: [A: issue mask(it+1) dwordx2 + STAGE(it+2)] [B: compute buf(it) w/ mask regs]
// [C: s_waitcnt vmcnt(5) (drains stage(it+1), leaves mask+stage(it+2)) ; s_barrier].
__global__ __launch_bounds__(256) void k_attn(
    const u16* __restrict__ Qp, const u16* __restrict__ Kp, const u16* __restrict__ Vt,
    const u32* __restrict__ mbits, u16* __restrict__ AO)
{
  __shared__ __align__(16) u16 KT[3][64 * 64];
  __shared__ __align__(16) u16 VT[3][64 * 64];
  const int qt = blockIdx.x, bh = blockIdx.y;
  const int b = bh >> 3, h = bh & 7;
  const int t = threadIdx.x, l = t & 63, w = t >> 6;
  const int l15 = l & 15, lg = l >> 4;

  const int srow = t >> 3;
  const int scol8 = t & 7;
  const int scol = (scol8 ^ (srow & 7)) * 8;
  const int kpr = (srow >> 5) * 32 + (((srow >> 4) & 1) * 4) + (((srow & 15) >> 2) * 8) + (srow & 3);
  const u16* gK = Kp + (size_t)(b * N_ + kpr) * DOUT + h * HD_ + scol;
  const u16* gV = Vt + (size_t)(b * 512 + h * HD_ + srow) * M_ + scol;

  const int qrow = qt * 64 + w * 16 + l15;
  const bf16x8 qf0 = *(const bf16x8*)&Qp[((size_t)(b * N_) + qrow) * DOUT + h * HD_ + lg * 8];
  const bf16x8 qf1 = *(const bf16x8*)&Qp[((size_t)(b * N_) + qrow) * DOUT + h * HD_ + 32 + lg * 8];
  const u32* mrow = mbits + ((size_t)(b * N_) + qrow) * (M_ / 32);

  f32x4 o[4] = {};
  f32x4 lacc = {};
  union U8 { u32 u[4]; bf16x8 v; };
  U8 ones;
  ones.u[0] = ones.u[1] = ones.u[2] = ones.u[3] = 0x3F803F80u;

  #define STAGE(buf_, m0_) do {                                   \
    const u16* gk_ = gK + (size_t)(m0_) * DOUT;                   \
    const u16* gv_ = gV + (m0_);                                  \
    u16* lk_ = &KT[buf_][t * 8];                                  \
    u16* lv_ = &VT[buf_][t * 8];                                  \
    gld16(lk_, gk_);                                              \
    gld16(lk_ + 2048, gk_ + (size_t)32 * DOUT);                   \
    gld16(lv_, gv_);                                              \
    gld16(lv_ + 2048, gv_ + (size_t)32 * M_);                     \
  } while (0)

  // prologue: mask(0) [1 op] + stage(0) [4] + stage(1) [4] -> drain through stage(0)
  u32x2 mc = *(const u32x2*)&mrow[0];
  STAGE(0, 0);
  STAGE(1, 64);
  __builtin_amdgcn_sched_barrier(0);
  asm volatile("s_waitcnt vmcnt(4)" ::: "memory");
  __builtin_amdgcn_sched_barrier(0);
  __builtin_amdgcn_s_barrier();
  __builtin_amdgcn_sched_barrier(0);

  for (int it = 0; it < 32; ++it) {
    const int cur = it % 3;
    const u16* Kb = KT[cur];
    const u16* Vb = VT[cur];

    // --- phase A: prefetch next mask word pair + stage tile it+2 ---
    u32x2 mn = {0u, 0u};
    if (it + 1 < 32) mn = *(const u32x2*)&mrow[2 * (it + 1)];
    if (it + 2 < 32) STAGE((it + 2) % 3, (it + 2) * 64);
    __builtin_amdgcn_sched_barrier(0);

    // --- phase B: compute on buf cur with mask regs mc ---
    const int xs = l15 & 7;
    U8 pa[2];
    #pragma unroll
    for (int kbk = 0; kbk < 2; ++kbk) {
      f32x4 sS[2];
      #pragma unroll
      for (int u = 0; u < 2; ++u) {
        const int row = kbk * 32 + u * 16 + l15;
        const bf16x8 a0 = *(const bf16x8*)&Kb[row * 64 + ((lg ^ xs) * 8)];
        const bf16x8 a1 = *(const bf16x8*)&Kb[row * 64 + (((4 + lg) ^ xs) * 8)];
        f32x4 zz = {};
        zz = __builtin_amdgcn_mfma_f32_16x16x32_bf16(a0, qf0, zz, 0, 0, 0);
        zz = __builtin_amdgcn_mfma_f32_16x16x32_bf16(a1, qf1, zz, 0, 0, 0);
        sS[u] = zz;
      }
      const u32 mw = kbk ? mc[1] : mc[0];
      float e[8];
      #pragma unroll
      for (int u = 0; u < 2; ++u)
        #pragma unroll
        for (int r = 0; r < 4; ++r) {
          const int bit = lg * 8 + u * 4 + r;
          float p = EXP2(sS[u][r]);
          e[u * 4 + r] = ((mw >> bit) & 1u) ? p : 0.f;
        }
      pa[kbk].u[0] = pkbf(e[0], e[1]);
      pa[kbk].u[1] = pkbf(e[2], e[3]);
      pa[kbk].u[2] = pkbf(e[4], e[5]);
      pa[kbk].u[3] = pkbf(e[6], e[7]);
    }
    lacc = __builtin_amdgcn_mfma_f32_16x16x32_bf16(ones.v, pa[0].v, lacc, 0, 0, 0);
    lacc = __builtin_amdgcn_mfma_f32_16x16x32_bf16(ones.v, pa[1].v, lacc, 0, 0, 0);
    #pragma unroll
    for (int nd = 0; nd < 4; ++nd) {
      const int vrow = nd * 16 + l15;
      const bf16x8 vb0 = *(const bf16x8*)&Vb[vrow * 64 + ((lg ^ xs) * 8)];
      const bf16x8 vb1 = *(const bf16x8*)&Vb[vrow * 64 + (((4 + lg) ^ xs) * 8)];
      o[nd] = __builtin_amdgcn_mfma_f32_16x16x32_bf16(vb0, pa[0].v, o[nd], 0, 0, 0);
      o[nd] = __builtin_amdgcn_mfma_f32_16x16x32_bf16(vb1, pa[1].v, o[nd], 0, 0, 0);
    }
    mc = mn;

    // --- phase C: counted drain + barrier (skip after last iter) ---
    __builtin_amdgcn_sched_barrier(0);
    if (it < 30) {
      asm volatile("s_waitcnt vmcnt(5)" ::: "memory");   // drain stage(it+1); keep mask + stage(it+2)
      __builtin_amdgcn_sched_barrier(0);
      __builtin_amdgcn_s_barrier();
      __builtin_amdgcn_sched_barrier(0);
    } else if (it == 30) {
      asm volatile("s_waitcnt vmcnt(1)" ::: "memory");   // drain stage(31); keep mask(31)
      __builtin_amdgcn_sched_barrier(0);
      __builtin_amdgcn_s_barrier();
      __builtin_amdgcn_sched_barrier(0);
    }
  }

  const float ls = lacc[0];
  const float rq = ls > 0.f ? 1.f / ls : 0.f;
  const size_t obase = ((size_t)(b * N_) + qrow) * DOUT + h * HD_;
  #pragma unroll
  for (int nd = 0; nd < 4; ++nd) {
    u32x2 pr;
    pr[0] = pkbf(o[nd][0] * rq, o[nd][1] * rq);
    pr[1] = pkbf(o[nd][2] * rq, o[nd][3] * rq);
    *(u32x2*)&AO[obase + nd * 16 + lg * 4] = pr;
  }
  #undef STAGE
}

// ---------------- output projection + bias + residual(bf16 qb) -> X (bf16), double-buffered ----------------
__global__ __launch_bounds__(256) void k_gemm_out(
    const u16* __restrict__ A, const u16* __restrict__ W,
    const float* __restrict__ bO, const u16* __restrict__ qb,
    u16* __restrict__ X)
{
  __shared__ __align__(16) u16 At[2][128 * 64];
  __shared__ __align__(16) u16 Bt[2][128 * 64];
  const int bm = blockIdx.y, bn = blockIdx.x;
  const int t = threadIdx.x, l = t & 63;
  const int w = t >> 6, wr = w >> 1, wc = w & 1;
  const int l15 = l & 15, lg = l >> 4;
  f32x4 acc[4][4] = {};
  const u16* ga = A + (size_t)(bm * 128 + (t >> 3)) * DOUT + (t & 7) * 8;
  const u16* gb = W + (size_t)(bn * 128 + (t >> 3)) * DOUT + (t & 7) * 8;

  #define STG(buf_, k0_) do {                                           \
    u16* la_ = &At[buf_][t * 8];                                        \
    u16* lb_ = &Bt[buf_][t * 8];                                        \
    _Pragma("unroll")                                                   \
    for (int s2 = 0; s2 < 4; ++s2) {                                    \
      gld16(la_ + s2 * 2048, ga + (size_t)s2 * 32 * DOUT + (k0_));      \
      gld16(lb_ + s2 * 2048, gb + (size_t)s2 * 32 * DOUT + (k0_));      \
    }                                                                   \
  } while (0)

  STG(0, 0);
  __syncthreads();
  for (int kt = 0; kt < 8; ++kt) {
    const int buf = kt & 1;
    if (kt + 1 < 8) STG(buf ^ 1, (kt + 1) * 64);
    const u16* rowT = &Bt[buf][wc * 64 * 64];   // W rows as A-operand
    const u16* colT = &At[buf][wr * 64 * 64];
    bf16x8 rf[4][2], cf[4][2];
    #pragma unroll
    for (int i = 0; i < 4; ++i)
      #pragma unroll
      for (int c = 0; c < 2; ++c)
        rf[i][c] = *(const bf16x8*)&rowT[(i * 16 + l15) * 64 + c * 32 + lg * 8];
    #pragma unroll
    for (int j = 0; j < 4; ++j)
      #pragma unroll
      for (int c = 0; c < 2; ++c)
        cf[j][c] = *(const bf16x8*)&colT[(j * 16 + l15) * 64 + c * 32 + lg * 8];
    #pragma unroll
    for (int i = 0; i < 4; ++i)
      #pragma unroll
      for (int j = 0; j < 4; ++j) {
        acc[i][j] = __builtin_amdgcn_mfma_f32_16x16x32_bf16(rf[i][0], cf[j][0], acc[i][j], 0, 0, 0);
        acc[i][j] = __builtin_amdgcn_mfma_f32_16x16x32_bf16(rf[i][1], cf[j][1], acc[i][j], 0, 0, 0);
      }
    __syncthreads();
  }
  #undef STG
  #pragma unroll
  for (int i = 0; i < 4; ++i) {
    const int o0 = bn * 128 + wc * 64 + i * 16 + lg * 4;
    const f32x4 bo4 = *(const f32x4*)&bO[o0];
    #pragma unroll
    for (int j = 0; j < 4; ++j) {
      const int m = bm * 128 + wr * 64 + j * 16 + l15;
      const size_t idx = (size_t)m * DOUT + o0;
      const u16x4 qv = *(const u16x4*)&qb[idx];
      u32x2 pr;
      pr[0] = pkbf(acc[i][j][0] + bo4[0] + bf2f(qv[0]), acc[i][j][1] + bo4[1] + bf2f(qv[1]));
      pr[1] = pkbf(acc[i][j][2] + bo4[2] + bf2f(qv[2]), acc[i][j][3] + bo4[3] + bf2f(qv[3]));
      *(u32x2*)&X[idx] = pr;
    }
  }
}

// ---------------- LayerNorm (one wave per row, bf16 input) ----------------
__global__ __launch_bounds__(256) void k_ln(
    const u16* __restrict__ X, const float* __restrict__ gamma,
    const float* __restrict__ beta, float* __restrict__ out)
{
  const int w = threadIdx.x >> 6, l = threadIdx.x & 63;
  const int row = blockIdx.x * 4 + w;
  const bf16x8 xv = *(const bf16x8*)(X + (size_t)row * DOUT + l * 8);
  float xf[8];
  #pragma unroll
  for (int i = 0; i < 8; ++i) xf[i] = bf2f((u16)xv[i]);
  float s = 0.f, q = 0.f;
  #pragma unroll
  for (int i = 0; i < 8; ++i) { s += xf[i]; q += xf[i] * xf[i]; }
  #pragma unroll
  for (int m = 1; m < 64; m <<= 1) { s += __shfl_xor(s, m); q += __shfl_xor(q, m); }
  const float mean = s * (1.f / 512.f);
  const float var = q * (1.f / 512.f) - mean * mean;
  const float rstd = rsqrtf(var + 1e-5f);
  f32x4 g1 = *(const f32x4*)(gamma + l * 8);
  f32x4 g2 = *(const f32x4*)(gamma + l * 8 + 4);
  f32x4 e1 = *(const f32x4*)(beta + l * 8);
  f32x4 e2 = *(const f32x4*)(beta + l * 8 + 4);
  f32x4 r1, r2;
  #pragma unroll
  for (int i = 0; i < 4; ++i) {
    r1[i] = (xf[i] - mean) * rstd * g1[i] + e1[i];
    r2[i] = (xf[i + 4] - mean) * rstd * g2[i] + e2[i];
  }
  float* op = out + (size_t)row * DOUT + l * 8;
  *(f32x4*)(op) = r1;
  *(f32x4*)(op + 4) = r2;
}

// ---------------- host ----------------
extern "C" void kernel_launch(void* const* d_in, const int* in_sizes, int n_in,
                              void* d_out, int out_size, void* d_ws, size_t ws_size,
                              hipStream_t stream)
{
  const float* query = (const float*)d_in[0];
  const float* key   = (const float*)d_in[1];
  const float* value = (const float*)d_in[2];
  const int*   mask  = (const int*)d_in[3];
  const float* WQ    = (const float*)d_in[4];
  const float* WK    = (const float*)d_in[5];
  const float* WV    = (const float*)d_in[6];
  const float* WO    = (const float*)d_in[7];
  const float* bO    = (const float*)d_in[8];
  const float* gamma = (const float*)d_in[9];
  const float* beta  = (const float*)d_in[10];
  float* out = (float*)d_out;

  char* ws = (char*)d_ws;
  size_t off = 0;
  auto alloc = [&](size_t bytes) -> char* {
    char* p = ws + off;
    off += (bytes + 255) & ~(size_t)255;
    return p;
  };
  u16* qb  = (u16*)alloc((size_t)ROWS * DIN * 2);          // live: residual for gemm_out
  u16* kb  = (u16*)alloc((size_t)ROWS * DIN * 2);          // dead after qkv -> X aliases
  u16* vb  = (u16*)alloc((size_t)ROWS * DIN * 2);          // dead after qkv -> AO aliases
  u16* wq  = (u16*)alloc((size_t)DOUT * DIN * 2);
  u16* wk  = (u16*)alloc((size_t)DOUT * DIN * 2);
  u16* wv  = (u16*)alloc((size_t)DOUT * DIN * 2);
  u16* wo  = (u16*)alloc((size_t)DOUT * DIN * 2);
  u16* Qp  = (u16*)alloc((size_t)ROWS * DOUT * 2);
  u16* Kp  = (u16*)alloc((size_t)ROWS * DOUT * 2);
  u16* Vt  = (u16*)alloc((size_t)ROWS * DOUT * 2);
  u32* mb  = (u32*)alloc((size_t)B_ * N_ * (M_ / 32) * 4);
  u16* AO  = vb;                                           // alias
  u16* X   = kb;                                           // alias (bf16)

  k_prep     <<<23040, 256, 0, stream>>>(query, key, value, WQ, WK, WV, WO, mask,
                                         qb, kb, vb, wq, wk, wv, wo, mb);
  k_gemm_qkv <<<dim3(4, 64, 3), 256, 0, stream>>>(qb, kb, vb, wq, wk, wv, Qp, Kp, Vt);
  k_attn     <<<dim3(32, 32), 256, 0, stream>>>(Qp, Kp, Vt, mb, AO);
  k_gemm_out <<<dim3(4, 64), 256, 0, stream>>>(AO, wo, bO, qb, X);
  k_ln       <<<2048, 256, 0, stream>>>(X, gamma, beta, out);
}

// Round 6
// 263.250 us; speedup vs baseline: 1.0905x; 1.0905x over previous
//
#include <hip/hip_runtime.h>
#include <stdint.h>

#define B_   4
#define N_   2048
#define M_   2048
#define DIN  512
#define DOUT 512
#define H_   8
#define HD_  64
#define ROWS (B_ * N_)   // 8192

typedef __attribute__((ext_vector_type(8))) short bf16x8;
typedef __attribute__((ext_vector_type(4))) float f32x4;
typedef __attribute__((ext_vector_type(2))) unsigned int u32x2;
typedef __attribute__((ext_vector_type(4))) unsigned short u16x4;
typedef unsigned short u16;
typedef unsigned int   u32;

#if __has_builtin(__builtin_amdgcn_exp2f)
#define EXP2(x) __builtin_amdgcn_exp2f(x)
#else
#define EXP2(x) exp2f(x)
#endif

__device__ __forceinline__ u16 f2bf(float x) {
  union { float f; u32 u; } v; v.f = x;
  u32 r = (v.u + 0x7FFFu + ((v.u >> 16) & 1u)) >> 16;
  return (u16)r;
}

__device__ __forceinline__ float bf2f(u16 x) {
  union { u32 u; float f; } v; v.u = ((u32)x) << 16;
  return v.f;
}

__device__ __forceinline__ u32 pkbf(float a, float b) {
  u32 r;
  asm("v_cvt_pk_bf16_f32 %0, %1, %2" : "=v"(r) : "v"(a), "v"(b));
  return r;
}

__device__ __forceinline__ void gld16(u16* lds, const u16* g) {
  __builtin_amdgcn_global_load_lds((const __attribute__((address_space(1))) u32*)g,
                                   (__attribute__((address_space(3))) u32*)lds, 16, 0, 0);
}

// ---------------- prep: f32 -> bf16 converts + balanced mask bit-pack ----------------
__global__ __launch_bounds__(256) void k_prep(
    const float* __restrict__ q, const float* __restrict__ k, const float* __restrict__ v,
    const float* __restrict__ wq_, const float* __restrict__ wk_,
    const float* __restrict__ wv_, const float* __restrict__ wo_,
    const int* __restrict__ mask,
    u16* __restrict__ qb, u16* __restrict__ kb, u16* __restrict__ vb,
    u16* __restrict__ wqb, u16* __restrict__ wkb, u16* __restrict__ wvb, u16* __restrict__ wob,
    u32* __restrict__ mbits)
{
  const int id = blockIdx.x;
  if (id >= 6656) {                      // mask pack: 16384 blocks x 4 waves x 4 iters x 64 ints
    const int id2 = id - 6656;
    const int lane = threadIdx.x & 63;
    const int gw = id2 * 4 + (threadIdx.x >> 6);      // 0..65535
    #pragma unroll
    for (int it2 = 0; it2 < 4; ++it2) {
      long pos = ((long)gw * 4 + it2) * 64 + lane;
      int mv = mask[pos];
      unsigned long long bal = __ballot(mv != 0);
      if ((lane & 31) == 0) mbits[pos >> 5] = (u32)(bal >> lane);
    }
    return;
  }
  const float* s; u16* d; size_t i;
  if (id < 6144) {                       // q/k/v: 3 x 4,194,304 elems
    const int seg = id >> 11;
    s = seg == 0 ? q : seg == 1 ? k : v;
    d = seg == 0 ? qb : seg == 1 ? kb : vb;
    i = (size_t)(id & 2047) * 2048 + threadIdx.x * 8;
  } else {                               // weights: 4 x 262,144 elems
    const int wid = id - 6144;
    const int seg = wid >> 7;
    s = seg == 0 ? wq_ : seg == 1 ? wk_ : seg == 2 ? wv_ : wo_;
    d = seg == 0 ? wqb : seg == 1 ? wkb : seg == 2 ? wvb : wob;
    i = (size_t)(wid & 127) * 2048 + threadIdx.x * 8;
  }
  f32x4 x = *(const f32x4*)(s + i);
  f32x4 y = *(const f32x4*)(s + i + 4);
  bf16x8 r;
  r[0] = (short)f2bf(x[0]); r[1] = (short)f2bf(x[1]);
  r[2] = (short)f2bf(x[2]); r[3] = (short)f2bf(x[3]);
  r[4] = (short)f2bf(y[0]); r[5] = (short)f2bf(y[1]);
  r[6] = (short)f2bf(y[2]); r[7] = (short)f2bf(y[3]);
  *(bf16x8*)(d + i) = r;
}

// ---------------- QKV projection GEMM (128x128 tile, BK=64), double-buffered, XCD swizzle ----------------
// z=0: Q [m][o] scaled by 0.125*log2(e); z=1: K [m][o]; z=2: V transposed [b*512+o][s].
__global__ __launch_bounds__(256) void k_gemm_qkv(
    const u16* __restrict__ Aq, const u16* __restrict__ Ak, const u16* __restrict__ Av,
    const u16* __restrict__ Wq, const u16* __restrict__ Wk, const u16* __restrict__ Wv,
    u16* __restrict__ Qo, u16* __restrict__ Ko, u16* __restrict__ Vt)
{
  __shared__ __align__(16) u16 At[2][128 * 64];
  __shared__ __align__(16) u16 Bt[2][128 * 64];
  // chunked XCD swizzle: 768 blocks = 8 XCDs x 96-block contiguous chunks
  const int swz = (blockIdx.x & 7) * 96 + (blockIdx.x >> 3);
  const int z = swz >> 8;
  const int bm = (swz & 255) >> 2, bn = swz & 3;
  const u16* A = z == 0 ? Aq : z == 1 ? Ak : Av;
  const u16* W = z == 0 ? Wq : z == 1 ? Wk : Wv;
  const int t = threadIdx.x, l = t & 63;
  const int w = t >> 6, wr = w >> 1, wc = w & 1;
  const int l15 = l & 15, lg = l >> 4;
  f32x4 acc[4][4] = {};
  const u16* ga = A + (size_t)(bm * 128 + (t >> 3)) * DIN + (t & 7) * 8;
  const u16* gb = W + (size_t)(bn * 128 + (t >> 3)) * DIN + (t & 7) * 8;

  #define STG(buf_, k0_) do {                                           \
    u16* la_ = &At[buf_][t * 8];                                        \
    u16* lb_ = &Bt[buf_][t * 8];                                        \
    _Pragma("unroll")                                                   \
    for (int s2 = 0; s2 < 4; ++s2) {                                    \
      gld16(la_ + s2 * 2048, ga + (size_t)s2 * 32 * DIN + (k0_));       \
      gld16(lb_ + s2 * 2048, gb + (size_t)s2 * 32 * DIN + (k0_));       \
    }                                                                   \
  } while (0)

  STG(0, 0);
  __syncthreads();
  for (int kt = 0; kt < 8; ++kt) {
    const int buf = kt & 1;
    if (kt + 1 < 8) STG(buf ^ 1, (kt + 1) * 64);
    const u16* rowT = (z < 2) ? &Bt[buf][wc * 64 * 64] : &At[buf][wr * 64 * 64];
    const u16* colT = (z < 2) ? &At[buf][wr * 64 * 64] : &Bt[buf][wc * 64 * 64];
    bf16x8 rf[4][2], cf[4][2];
    #pragma unroll
    for (int i = 0; i < 4; ++i)
      #pragma unroll
      for (int c = 0; c < 2; ++c)
        rf[i][c] = *(const bf16x8*)&rowT[(i * 16 + l15) * 64 + c * 32 + lg * 8];
    #pragma unroll
    for (int j = 0; j < 4; ++j)
      #pragma unroll
      for (int c = 0; c < 2; ++c)
        cf[j][c] = *(const bf16x8*)&colT[(j * 16 + l15) * 64 + c * 32 + lg * 8];
    #pragma unroll
    for (int i = 0; i < 4; ++i)
      #pragma unroll
      for (int j = 0; j < 4; ++j) {
        acc[i][j] = __builtin_amdgcn_mfma_f32_16x16x32_bf16(rf[i][0], cf[j][0], acc[i][j], 0, 0, 0);
        acc[i][j] = __builtin_amdgcn_mfma_f32_16x16x32_bf16(rf[i][1], cf[j][1], acc[i][j], 0, 0, 0);
      }
    __syncthreads();
  }
  #undef STG
  if (z < 2) {
    u16* C = z == 0 ? Qo : Ko;
    const float scl = z == 0 ? 0.18033688f : 1.0f;   // 1/sqrt(HD) * log2(e) folded into Q
    #pragma unroll
    for (int i = 0; i < 4; ++i) {
      const int o0 = bn * 128 + wc * 64 + i * 16 + lg * 4;
      #pragma unroll
      for (int j = 0; j < 4; ++j) {
        const int m = bm * 128 + wr * 64 + j * 16 + l15;
        u32x2 pr;
        pr[0] = pkbf(acc[i][j][0] * scl, acc[i][j][1] * scl);
        pr[1] = pkbf(acc[i][j][2] * scl, acc[i][j][3] * scl);
        *(u32x2*)&C[(size_t)m * DOUT + o0] = pr;
      }
    }
  } else {
    #pragma unroll
    for (int i = 0; i < 4; ++i) {
      const int mm = bm * 128 + wr * 64 + i * 16 + lg * 4;
      const int bb = mm >> 11, s = mm & 2047;
      #pragma unroll
      for (int j = 0; j < 4; ++j) {
        const int o = bn * 128 + wc * 64 + j * 16 + l15;
        u32x2 pr;
        pr[0] = pkbf(acc[i][j][0], acc[i][j][1]);
        pr[1] = pkbf(acc[i][j][2], acc[i][j][3]);
        *(u32x2*)&Vt[(size_t)(bb * 512 + o) * M_ + s] = pr;
      }
    }
  }
}

// ---------------- attention v6: 8 waves / 128 q-rows per block, 2-buffer, XCD swizzle ----------------
__global__ __launch_bounds__(512, 4) void k_attn(
    const u16* __restrict__ Qp, const u16* __restrict__ Kp, const u16* __restrict__ Vt,
    const u32* __restrict__ mbits, u16* __restrict__ AO)
{
  __shared__ __align__(16) u16 KT[2][64 * 64];
  __shared__ __align__(16) u16 VT[2][64 * 64];
  // chunked XCD swizzle: 512 blocks = 8 XCDs x 64-block chunks -> each XCD owns 4 (b,h) slices
  const int swz = (blockIdx.x & 7) * 64 + (blockIdx.x >> 3);
  const int qt = swz & 15, bh = swz >> 4;
  const int b = bh >> 3, h = bh & 7;
  const int t = threadIdx.x, l = t & 63, w = t >> 6;
  const int l15 = l & 15, lg = l >> 4;

  // staging geometry: 512 threads cover one full 64x64 tile (srow 0..63, 16B seg scol8)
  const int srow = t >> 3;
  const int scol8 = t & 7;
  const int scol = (scol8 ^ (srow & 7)) * 8;            // inverse-swizzled source column
  // K-row permutation so swapped-QK^T C-layout == PV B-frag (P) layout
  const int kpr = (srow >> 5) * 32 + (((srow >> 4) & 1) * 4) + (((srow & 15) >> 2) * 8) + (srow & 3);
  const u16* gK = Kp + (size_t)(b * N_ + kpr) * DOUT + h * HD_ + scol;
  const u16* gV = Vt + (size_t)(b * 512 + h * HD_ + srow) * M_ + scol;

  const int qrow = qt * 128 + w * 16 + l15;
  const bf16x8 qf0 = *(const bf16x8*)&Qp[((size_t)(b * N_) + qrow) * DOUT + h * HD_ + lg * 8];
  const bf16x8 qf1 = *(const bf16x8*)&Qp[((size_t)(b * N_) + qrow) * DOUT + h * HD_ + 32 + lg * 8];
  const u32* mrow = mbits + ((size_t)(b * N_) + qrow) * (M_ / 32);

  f32x4 o[4] = {};
  f32x4 lacc = {};
  union U8 { u32 u[4]; bf16x8 v; };
  U8 ones;
  ones.u[0] = ones.u[1] = ones.u[2] = ones.u[3] = 0x3F803F80u;

  #define STAGE(buf_, m0_) do {                                   \
    gld16(&KT[buf_][t * 8], gK + (size_t)(m0_) * DOUT);           \
    gld16(&VT[buf_][t * 8], gV + (m0_));                          \
  } while (0)

  STAGE(0, 0);
  __syncthreads();

  for (int it = 0; it < 32; ++it) {
    const int buf = it & 1;
    const int m0 = it * 64;
    if (it + 1 < 32) STAGE(buf ^ 1, m0 + 64);

    const u32x2 mc = *(const u32x2*)&mrow[2 * it];
    const u16* Kb = KT[buf];
    const u16* Vb = VT[buf];
    const int xs = l15 & 7;

    U8 pa[2];
    #pragma unroll
    for (int kbk = 0; kbk < 2; ++kbk) {
      f32x4 sS[2];
      __builtin_amdgcn_s_setprio(1);
      #pragma unroll
      for (int u = 0; u < 2; ++u) {
        const int row = kbk * 32 + u * 16 + l15;
        const bf16x8 a0 = *(const bf16x8*)&Kb[row * 64 + ((lg ^ xs) * 8)];
        const bf16x8 a1 = *(const bf16x8*)&Kb[row * 64 + (((4 + lg) ^ xs) * 8)];
        f32x4 zz = {};
        zz = __builtin_amdgcn_mfma_f32_16x16x32_bf16(a0, qf0, zz, 0, 0, 0);
        zz = __builtin_amdgcn_mfma_f32_16x16x32_bf16(a1, qf1, zz, 0, 0, 0);
        sS[u] = zz;
      }
      __builtin_amdgcn_s_setprio(0);
      const u32 mw = kbk ? mc[1] : mc[0];
      float e[8];
      #pragma unroll
      for (int u = 0; u < 2; ++u)
        #pragma unroll
        for (int r = 0; r < 4; ++r) {
          const int bit = lg * 8 + u * 4 + r;
          float p = EXP2(sS[u][r]);
          e[u * 4 + r] = ((mw >> bit) & 1u) ? p : 0.f;
        }
      pa[kbk].u[0] = pkbf(e[0], e[1]);
      pa[kbk].u[1] = pkbf(e[2], e[3]);
      pa[kbk].u[2] = pkbf(e[4], e[5]);
      pa[kbk].u[3] = pkbf(e[6], e[7]);
    }
    __builtin_amdgcn_s_setprio(1);
    lacc = __builtin_amdgcn_mfma_f32_16x16x32_bf16(ones.v, pa[0].v, lacc, 0, 0, 0);
    lacc = __builtin_amdgcn_mfma_f32_16x16x32_bf16(ones.v, pa[1].v, lacc, 0, 0, 0);
    #pragma unroll
    for (int nd = 0; nd < 4; ++nd) {
      const int vrow = nd * 16 + l15;
      const bf16x8 vb0 = *(const bf16x8*)&Vb[vrow * 64 + ((lg ^ xs) * 8)];
      const bf16x8 vb1 = *(const bf16x8*)&Vb[vrow * 64 + (((4 + lg) ^ xs) * 8)];
      o[nd] = __builtin_amdgcn_mfma_f32_16x16x32_bf16(vb0, pa[0].v, o[nd], 0, 0, 0);
      o[nd] = __builtin_amdgcn_mfma_f32_16x16x32_bf16(vb1, pa[1].v, o[nd], 0, 0, 0);
    }
    __builtin_amdgcn_s_setprio(0);
    __syncthreads();
  }

  const float ls = lacc[0];
  const float rq = ls > 0.f ? 1.f / ls : 0.f;
  const size_t obase = ((size_t)(b * N_) + qrow) * DOUT + h * HD_;
  #pragma unroll
  for (int nd = 0; nd < 4; ++nd) {
    u32x2 pr;
    pr[0] = pkbf(o[nd][0] * rq, o[nd][1] * rq);
    pr[1] = pkbf(o[nd][2] * rq, o[nd][3] * rq);
    *(u32x2*)&AO[obase + nd * 16 + lg * 4] = pr;
  }
  #undef STAGE
}

// ---------------- output projection + bias + residual(bf16 qb) -> X (bf16), dbuf, XCD swizzle ----------------
__global__ __launch_bounds__(256) void k_gemm_out(
    const u16* __restrict__ A, const u16* __restrict__ W,
    const float* __restrict__ bO, const u16* __restrict__ qb,
    u16* __restrict__ X)
{
  __shared__ __align__(16) u16 At[2][128 * 64];
  __shared__ __align__(16) u16 Bt[2][128 * 64];
  const int swz = (blockIdx.x & 7) * 32 + (blockIdx.x >> 3);   // 256 = 8 x 32
  const int bm = swz >> 2, bn = swz & 3;
  const int t = threadIdx.x, l = t & 63;
  const int w = t >> 6, wr = w >> 1, wc = w & 1;
  const int l15 = l & 15, lg = l >> 4;
  f32x4 acc[4][4] = {};
  const u16* ga = A + (size_t)(bm * 128 + (t >> 3)) * DOUT + (t & 7) * 8;
  const u16* gb = W + (size_t)(bn * 128 + (t >> 3)) * DOUT + (t & 7) * 8;

  #define STG(buf_, k0_) do {                                           \
    u16* la_ = &At[buf_][t * 8];                                        \
    u16* lb_ = &Bt[buf_][t * 8];                                        \
    _Pragma("unroll")                                                   \
    for (int s2 = 0; s2 < 4; ++s2) {                                    \
      gld16(la_ + s2 * 2048, ga + (size_t)s2 * 32 * DOUT + (k0_));      \
      gld16(lb_ + s2 * 2048, gb + (size_t)s2 * 32 * DOUT + (k0_));      \
    }                                                                   \
  } while (0)

  STG(0, 0);
  __syncthreads();
  for (int kt = 0; kt < 8; ++kt) {
    const int buf = kt & 1;
    if (kt + 1 < 8) STG(buf ^ 1, (kt + 1) * 64);
    const u16* rowT = &Bt[buf][wc * 64 * 64];   // W rows as A-operand
    const u16* colT = &At[buf][wr * 64 * 64];
    bf16x8 rf[4][2], cf[4][2];
    #pragma unroll
    for (int i = 0; i < 4; ++i)
      #pragma unroll
      for (int c = 0; c < 2; ++c)
        rf[i][c] = *(const bf16x8*)&rowT[(i * 16 + l15) * 64 + c * 32 + lg * 8];
    #pragma unroll
    for (int j = 0; j < 4; ++j)
      #pragma unroll
      for (int c = 0; c < 2; ++c)
        cf[j][c] = *(const bf16x8*)&colT[(j * 16 + l15) * 64 + c * 32 + lg * 8];
    #pragma unroll
    for (int i = 0; i < 4; ++i)
      #pragma unroll
      for (int j = 0; j < 4; ++j) {
        acc[i][j] = __builtin_amdgcn_mfma_f32_16x16x32_bf16(rf[i][0], cf[j][0], acc[i][j], 0, 0, 0);
        acc[i][j] = __builtin_amdgcn_mfma_f32_16x16x32_bf16(rf[i][1], cf[j][1], acc[i][j], 0, 0, 0);
      }
    __syncthreads();
  }
  #undef STG
  #pragma unroll
  for (int i = 0; i < 4; ++i) {
    const int o0 = bn * 128 + wc * 64 + i * 16 + lg * 4;
    const f32x4 bo4 = *(const f32x4*)&bO[o0];
    #pragma unroll
    for (int j = 0; j < 4; ++j) {
      const int m = bm * 128 + wr * 64 + j * 16 + l15;
      const size_t idx = (size_t)m * DOUT + o0;
      const u16x4 qv = *(const u16x4*)&qb[idx];
      u32x2 pr;
      pr[0] = pkbf(acc[i][j][0] + bo4[0] + bf2f(qv[0]), acc[i][j][1] + bo4[1] + bf2f(qv[1]));
      pr[1] = pkbf(acc[i][j][2] + bo4[2] + bf2f(qv[2]), acc[i][j][3] + bo4[3] + bf2f(qv[3]));
      *(u32x2*)&X[idx] = pr;
    }
  }
}

// ---------------- LayerNorm (one wave per row, bf16 input) ----------------
__global__ __launch_bounds__(256) void k_ln(
    const u16* __restrict__ X, const float* __restrict__ gamma,
    const float* __restrict__ beta, float* __restrict__ out)
{
  const int w = threadIdx.x >> 6, l = threadIdx.x & 63;
  const int row = blockIdx.x * 4 + w;
  const bf16x8 xv = *(const bf16x8*)(X + (size_t)row * DOUT + l * 8);
  float xf[8];
  #pragma unroll
  for (int i = 0; i < 8; ++i) xf[i] = bf2f((u16)xv[i]);
  float s = 0.f, q = 0.f;
  #pragma unroll
  for (int i = 0; i < 8; ++i) { s += xf[i]; q += xf[i] * xf[i]; }
  #pragma unroll
  for (int m = 1; m < 64; m <<= 1) { s += __shfl_xor(s, m); q += __shfl_xor(q, m); }
  const float mean = s * (1.f / 512.f);
  const float var = q * (1.f / 512.f) - mean * mean;
  const float rstd = rsqrtf(var + 1e-5f);
  f32x4 g1 = *(const f32x4*)(gamma + l * 8);
  f32x4 g2 = *(const f32x4*)(gamma + l * 8 + 4);
  f32x4 e1 = *(const f32x4*)(beta + l * 8);
  f32x4 e2 = *(const f32x4*)(beta + l * 8 + 4);
  f32x4 r1, r2;
  #pragma unroll
  for (int i = 0; i < 4; ++i) {
    r1[i] = (xf[i] - mean) * rstd * g1[i] + e1[i];
    r2[i] = (xf[i + 4] - mean) * rstd * g2[i] + e2[i];
  }
  float* op = out + (size_t)row * DOUT + l * 8;
  *(f32x4*)(op) = r1;
  *(f32x4*)(op + 4) = r2;
}

// ---------------- host ----------------
extern "C" void kernel_launch(void* const* d_in, const int* in_sizes, int n_in,
                              void* d_out, int out_size, void* d_ws, size_t ws_size,
                              hipStream_t stream)
{
  const float* query = (const float*)d_in[0];
  const float* key   = (const float*)d_in[1];
  const float* value = (const float*)d_in[2];
  const int*   mask  = (const int*)d_in[3];
  const float* WQ    = (const float*)d_in[4];
  const float* WK    = (const float*)d_in[5];
  const float* WV    = (const float*)d_in[6];
  const float* WO    = (const float*)d_in[7];
  const float* bO    = (const float*)d_in[8];
  const float* gamma = (const float*)d_in[9];
  const float* beta  = (const float*)d_in[10];
  float* out = (float*)d_out;

  char* ws = (char*)d_ws;
  size_t off = 0;
  auto alloc = [&](size_t bytes) -> char* {
    char* p = ws + off;
    off += (bytes + 255) & ~(size_t)255;
    return p;
  };
  u16* qb  = (u16*)alloc((size_t)ROWS * DIN * 2);          // live: residual for gemm_out
  u16* kb  = (u16*)alloc((size_t)ROWS * DIN * 2);          // dead after qkv -> X aliases
  u16* vb  = (u16*)alloc((size_t)ROWS * DIN * 2);          // dead after qkv -> AO aliases
  u16* wq  = (u16*)alloc((size_t)DOUT * DIN * 2);
  u16* wk  = (u16*)alloc((size_t)DOUT * DIN * 2);
  u16* wv  = (u16*)alloc((size_t)DOUT * DIN * 2);
  u16* wo  = (u16*)alloc((size_t)DOUT * DIN * 2);
  u16* Qp  = (u16*)alloc((size_t)ROWS * DOUT * 2);
  u16* Kp  = (u16*)alloc((size_t)ROWS * DOUT * 2);
  u16* Vt  = (u16*)alloc((size_t)ROWS * DOUT * 2);
  u32* mb  = (u32*)alloc((size_t)B_ * N_ * (M_ / 32) * 4);
  u16* AO  = vb;                                           // alias
  u16* X   = kb;                                           // alias (bf16)

  k_prep     <<<23040, 256, 0, stream>>>(query, key, value, WQ, WK, WV, WO, mask,
                                         qb, kb, vb, wq, wk, wv, wo, mb);
  k_gemm_qkv <<<768, 256, 0, stream>>>(qb, kb, vb, wq, wk, wv, Qp, Kp, Vt);
  k_attn     <<<512, 512, 0, stream>>>(Qp, Kp, Vt, mb, AO);
  k_gemm_out <<<256, 256, 0, stream>>>(AO, wo, bO, qb, X);
  k_ln       <<<2048, 256, 0, stream>>>(X, gamma, beta, out);
}